// Round 6
// baseline (256.233 us; speedup 1.0000x reference)
//
#include <hip/hip_runtime.h>
#include <hip/hip_bf16.h>

// B=2, IMG_DIM=VOXEL_DIM=QK_DIM=256, H=W=64, N=4096.
// Inputs/outputs FP32; internal GEMMs bf16 MFMA (16x16x32).

typedef __hip_bfloat16 bf16;
typedef __attribute__((ext_vector_type(8))) short bf16x8;   // 8 bf16 = 4 VGPRs
typedef __attribute__((ext_vector_type(4))) float f32x4;

#define AS1 __attribute__((address_space(1)))
#define AS3 __attribute__((address_space(3)))

__device__ __forceinline__ void gld_lds16(const bf16* g, bf16* s) {
    // async global->LDS, 16B/lane; LDS dst = wave-uniform base + lane*16
    __builtin_amdgcn_global_load_lds((const AS1 void*)g, (AS3 void*)s, 16, 0, 0);
}

__device__ __forceinline__ bf16x8 cvt8(const float* __restrict__ p) {
    const float4 a = *(const float4*)p;
    const float4 b = *(const float4*)(p + 4);
    bf16 t[8];
    t[0] = __float2bfloat16(a.x); t[1] = __float2bfloat16(a.y);
    t[2] = __float2bfloat16(a.z); t[3] = __float2bfloat16(a.w);
    t[4] = __float2bfloat16(b.x); t[5] = __float2bfloat16(b.y);
    t[6] = __float2bfloat16(b.z); t[7] = __float2bfloat16(b.w);
    return *(const bf16x8*)t;
}

// Conflict-free LDS chunk swizzles (16B chunks). Measured r5: conflicts -> 0.
// BK=32 (4 chunks/row):
__device__ __forceinline__ int chunk_of(int row, int kc) {
    return ((row >> 3) << 5) + (kc << 3) + (row & 7);
}
// BK=64 (8 chunks/row):
__device__ __forceinline__ int chunk_of64(int row, int kc) {
    return ((row >> 3) << 6) + (kc << 3) + (row & 7);
}

// ---------------------------------------------------------------------------
// Kernel 1: projections. 512 blocks: blk = s*256 + b*128 + g*64 + ntile.
//   g=0: Q/Kt [n][o] (acc rows = o, packed b64 stores)
//   g=1: V    [o][p] (acc rows = n=p, packed b64 stores)
// ---------------------------------------------------------------------------
__global__ __launch_bounds__(256) void proj_kernel(
    const float* __restrict__ img, const float* __restrict__ pc,
    const float* __restrict__ Wq,  const float* __restrict__ bq,
    const float* __restrict__ Wk,  const float* __restrict__ bk,
    const float* __restrict__ Wvi, const float* __restrict__ bvi,
    const float* __restrict__ Wvp, const float* __restrict__ bvp,
    bf16* __restrict__ Qw, bf16* __restrict__ Ktw, bf16* __restrict__ Vall)
{
    __shared__ __align__(16) bf16 XT[64][264];   // [pos][cin], +8 pad

    const int blk = blockIdx.x;
    const int s   = blk >> 8;
    const int b   = (blk >> 7) & 1;
    const int g   = (blk >> 6) & 1;
    const int n0  = (blk & 63) * 64;
    const int tid = threadIdx.x;

    if (s == 0) {
        const float* src = img + b * 1048576;                 // [256][4096]
        for (int k = 0; k < 16; k++) {
            const int i = tid + k * 256;
            const int cin = i >> 4, nl4 = (i & 15) * 4;
            const float4 v = *(const float4*)&src[cin * 4096 + n0 + nl4];
            XT[nl4 + 0][cin] = __float2bfloat16(v.x);
            XT[nl4 + 1][cin] = __float2bfloat16(v.y);
            XT[nl4 + 2][cin] = __float2bfloat16(v.z);
            XT[nl4 + 3][cin] = __float2bfloat16(v.w);
        }
    } else {
        // pc[b][d][h][w][c]: ch = c*16+d, flat = d*65536 + n*16 + c
        const float* src = pc + b * 1048576;
        for (int k = 0; k < 16; k++) {
            const int d = k, u = tid;
            const int nl = u >> 2, c4 = (u & 3) * 4;
            const float4 v = *(const float4*)&src[d * 65536 + (n0 + nl) * 16 + c4];
            XT[nl][(c4 + 0) * 16 + d] = __float2bfloat16(v.x);
            XT[nl][(c4 + 1) * 16 + d] = __float2bfloat16(v.y);
            XT[nl][(c4 + 2) * 16 + d] = __float2bfloat16(v.z);
            XT[nl][(c4 + 3) * 16 + d] = __float2bfloat16(v.w);
        }
    }
    __syncthreads();

    const float* W  = s ? (g ? Wvp : Wk) : (g ? Wvi : Wq);
    const float* Bv = s ? (g ? bvp : bk) : (g ? bvi : bq);

    const int wv = tid >> 6, lane = tid & 63, l16 = lane & 15, quad = lane >> 4;
    const int ob = wv * 64;

    f32x4 acc[4][4] = {};

    for (int ks = 0; ks < 8; ks++) {
        const int k0 = ks * 32;
        bf16x8 af[4], wf[4];
        for (int ti = 0; ti < 4; ti++)
            af[ti] = *(const bf16x8*)&XT[ti * 16 + l16][k0 + quad * 8];
        for (int tj = 0; tj < 4; tj++)
            wf[tj] = cvt8(&W[(ob + tj * 16 + l16) * 256 + k0 + quad * 8]);
        if (g == 0) {
            for (int ti = 0; ti < 4; ti++)
                for (int tj = 0; tj < 4; tj++)
                    acc[ti][tj] = __builtin_amdgcn_mfma_f32_16x16x32_bf16(wf[tj], af[ti], acc[ti][tj], 0, 0, 0);
        } else {
            for (int ti = 0; ti < 4; ti++)
                for (int tj = 0; tj < 4; tj++)
                    acc[ti][tj] = __builtin_amdgcn_mfma_f32_16x16x32_bf16(af[ti], wf[tj], acc[ti][tj], 0, 0, 0);
        }
    }

    if (g == 0) {
        bf16* D1 = (s ? Ktw : Qw) + b * (4096 * 256);          // [n][o]
        for (int tj = 0; tj < 4; tj++) {
            const int o0 = ob + tj * 16 + quad * 4;
            const float4 bi = *(const float4*)&Bv[o0];
            for (int ti = 0; ti < 4; ti++) {
                const int n = n0 + ti * 16 + l16;
                bf16 pv[4];
                pv[0] = __float2bfloat16(acc[ti][tj][0] + bi.x);
                pv[1] = __float2bfloat16(acc[ti][tj][1] + bi.y);
                pv[2] = __float2bfloat16(acc[ti][tj][2] + bi.z);
                pv[3] = __float2bfloat16(acc[ti][tj][3] + bi.w);
                *(uint2*)&D1[n * 256 + o0] = *(const uint2*)pv;
            }
        }
    } else {
        bf16* D2 = Vall + b * (512 * 4096) + (s ? 256 * 4096 : 0);  // [c'][p]
        for (int tj = 0; tj < 4; tj++) {
            const int o = ob + tj * 16 + l16;
            const float bias = Bv[o];
            for (int ti = 0; ti < 4; ti++) {
                const int nl = ti * 16 + quad * 4;             // D row = quad*4+r
                bf16 pv[4];
                for (int r = 0; r < 4; r++)
                    pv[r] = __float2bfloat16(acc[ti][tj][r] + bias);
                *(uint2*)&D2[o * 4096 + n0 + nl] = *(const uint2*)pv;
            }
        }
    }
}

// ---------------------------------------------------------------------------
// Kernel 2: S^T = Kt.Q^T (A = Kt rows p, B = Q rows q; K=256) so the 4 acc
// regs are a p-run -> packed 8B stores of Pt[q][p] = exp(S). gld_lds staging
// with conflict-free swizzle. Lpart[b][q][strip64] via quad shuffles.
// No max-subtraction: |S| <= ~10; clamp 80 inert.
// ---------------------------------------------------------------------------
__global__ __launch_bounds__(256) void attn_s_kernel(
    const bf16* __restrict__ Qw, const bf16* __restrict__ Ktw,
    bf16* __restrict__ Pt, float* __restrict__ Lpart)
{
    __shared__ __align__(16) bf16 As[128 * 32];   // Kt rows (p)
    __shared__ __align__(16) bf16 Bs[128 * 32];   // Q rows (q)

    const int b  = blockIdx.z;
    const int p0 = blockIdx.x * 128;
    const int q0 = blockIdx.y * 128;
    const bf16* A = Ktw + b * (4096 * 256);
    const bf16* B = Qw  + b * (4096 * 256);

    const int tid = threadIdx.x;
    const int wv = tid >> 6, lane = tid & 63, l16 = lane & 15, quad = lane >> 4;
    const int wr = wv >> 1, wc = wv & 1;          // wr: p-half, wc: q-half

    const int srow = ((tid >> 5) << 3) | (tid & 7);   // staging row 0..63
    const int skc  = (tid >> 3) & 3;

    f32x4 acc[4][4] = {};

    for (int ks = 0; ks < 8; ks++) {
        const int k0 = ks * 32;
        gld_lds16(A + (p0 + srow     ) * 256 + k0 + skc * 8, As + tid * 8);
        gld_lds16(A + (p0 + 64 + srow) * 256 + k0 + skc * 8, As + (256 + tid) * 8);
        gld_lds16(B + (q0 + srow     ) * 256 + k0 + skc * 8, Bs + tid * 8);
        gld_lds16(B + (q0 + 64 + srow) * 256 + k0 + skc * 8, Bs + (256 + tid) * 8);
        __syncthreads();
        bf16x8 af[4], bfr[4];
        for (int t = 0; t < 4; t++) {
            const int Ra = wr * 64 + t * 16 + l16;
            const int Rb = wc * 64 + t * 16 + l16;
            af[t]  = *(const bf16x8*)&As[chunk_of(Ra, quad) * 8];
            bfr[t] = *(const bf16x8*)&Bs[chunk_of(Rb, quad) * 8];
        }
        for (int ti = 0; ti < 4; ti++)
            for (int tj = 0; tj < 4; tj++)
                acc[ti][tj] = __builtin_amdgcn_mfma_f32_16x16x32_bf16(af[ti], bfr[tj], acc[ti][tj], 0, 0, 0);
        __syncthreads();
    }

    bf16* Pdst = Pt + (size_t)b * 4096 * 4096;
    float lsum[4] = {0.f, 0.f, 0.f, 0.f};        // per tj (fixed q per lane)
    for (int ti = 0; ti < 4; ti++) {
        const int pr = p0 + wr * 64 + ti * 16 + quad * 4;
        for (int tj = 0; tj < 4; tj++) {
            const int q = q0 + wc * 64 + tj * 16 + l16;
            bf16 pv[4];
            float su = 0.0f;
            for (int r = 0; r < 4; r++) {
                const float e = __expf(fminf(acc[ti][tj][r], 80.0f));
                su += e;
                pv[r] = __float2bfloat16(e);
            }
            lsum[tj] += su;
            *(uint2*)&Pdst[(size_t)q * 4096 + pr] = *(const uint2*)pv;
        }
    }
    for (int tj = 0; tj < 4; tj++) {
        float v = lsum[tj];
        v += __shfl_xor(v, 16);
        v += __shfl_xor(v, 32);
        if (quad == 0) {
            const int q = q0 + wc * 64 + tj * 16 + l16;
            Lpart[(size_t)(b * 4096 + q) * 64 + blockIdx.x * 2 + wr] = v;
        }
    }
}

// ---------------------------------------------------------------------------
// Kernel 2b: Linv[b][q] = 1 / sum_strip Lpart  (8192 rows x 64 strips)
// ---------------------------------------------------------------------------
__global__ __launch_bounds__(256) void lred_kernel(
    const float* __restrict__ Lpart, float* __restrict__ Linv)
{
    const int row = blockIdx.x * 256 + threadIdx.x;           // [0, 8192)
    const float4* lp = (const float4*)&Lpart[(size_t)row * 64];
    float s = 0.0f;
    for (int i = 0; i < 16; i++) {
        const float4 v = lp[i];
        s += v.x + v.y + v.z + v.w;
    }
    Linv[row] = 1.0f / fmaxf(s, 1e-30f);
}

// ---------------------------------------------------------------------------
// Kernel 3a: O^T partials. A = Pt (64 q-rows), B = Vall (128 c-rows), BK=64,
// split-K=2 -> grid (64,4,4) = 1024 blocks (~4/CU, 16 waves/CU). 24 KB LDS.
// fp32 partials [s][b][c][q], packed f32x4 stores (regs are a q-run).
// ---------------------------------------------------------------------------
__global__ __launch_bounds__(256) void attn_o_splitk(
    const bf16* __restrict__ Pt, const bf16* __restrict__ Vall,
    float* __restrict__ Opart)
{
    __shared__ __align__(16) bf16 As[64 * 64];    // Pt q-rows (512 chunks)
    __shared__ __align__(16) bf16 Bs[128 * 64];   // Vall c-rows (1024 chunks)

    const int z = blockIdx.z;                     // b*2 + split
    const int b = z >> 1, s = z & 1;
    const int q0 = blockIdx.x * 64;
    const int c0 = blockIdx.y * 128;
    const bf16* A  = Pt   + (size_t)b * 4096 * 4096;
    const bf16* Bp = Vall + (size_t)b * 512 * 4096;

    const int tid = threadIdx.x;
    const int wv = tid >> 6, lane = tid & 63, l16 = lane & 15, quad = lane >> 4;
    const int wr = wv >> 1, wc = wv & 1;          // wr: q-half(32), wc: c-half(64)

    const int kbase = s * 2048;

    f32x4 acc[2][4] = {};

    for (int ks = 0; ks < 32; ks++) {
        const int k0 = kbase + ks * 64;
        for (int r = 0; r < 2; r++) {             // A: 512 chunks
            const int ch = r * 256 + tid;
            const int row = ((ch >> 6) << 3) | (ch & 7), kc = (ch >> 3) & 7;
            gld_lds16(A + (size_t)(q0 + row) * 4096 + k0 + kc * 8, As + ch * 8);
        }
        for (int r = 0; r < 4; r++) {             // B: 1024 chunks
            const int ch = r * 256 + tid;
            const int row = ((ch >> 6) << 3) | (ch & 7), kc = (ch >> 3) & 7;
            gld_lds16(Bp + (size_t)(c0 + row) * 4096 + k0 + kc * 8, Bs + ch * 8);
        }
        __syncthreads();
        for (int kk = 0; kk < 2; kk++) {
            const int kc = kk * 4 + quad;
            bf16x8 af[2], bfr[4];
            for (int t = 0; t < 2; t++) {
                const int Ra = wr * 32 + t * 16 + l16;
                af[t] = *(const bf16x8*)&As[chunk_of64(Ra, kc) * 8];
            }
            for (int t = 0; t < 4; t++) {
                const int Rb = wc * 64 + t * 16 + l16;
                bfr[t] = *(const bf16x8*)&Bs[chunk_of64(Rb, kc) * 8];
            }
            for (int ti = 0; ti < 2; ti++)
                for (int tj = 0; tj < 4; tj++)
                    acc[ti][tj] = __builtin_amdgcn_mfma_f32_16x16x32_bf16(af[ti], bfr[tj], acc[ti][tj], 0, 0, 0);
        }
        __syncthreads();
    }

    float* Od = Opart + (size_t)(s * 2 + b) * 512 * 4096;     // [c][q]
    for (int ti = 0; ti < 2; ti++) {
        const int q = q0 + wr * 32 + ti * 16 + quad * 4;      // q-run of 4
        for (int tj = 0; tj < 4; tj++) {
            const int c = c0 + wc * 64 + tj * 16 + l16;
            *(f32x4*)&Od[(size_t)c * 4096 + q] = acc[ti][tj];
        }
    }
}

// ---------------------------------------------------------------------------
// Kernel 3b: combine splits, apply Linv, scatter to the two outputs.
// ---------------------------------------------------------------------------
__global__ __launch_bounds__(256) void reduce_kernel(
    const float* __restrict__ Opart, const float* __restrict__ Linv,
    float* __restrict__ out)
{
    const int f = blockIdx.x * 256 + threadIdx.x;             // f32x4 index
    const size_t g = (size_t)f * 4;                           // [b][c][q] flat
    const int q4 = (int)(g & 4095);
    const int c  = (int)((g >> 12) & 511);
    const int b  = (int)(g >> 21);
    const float4 a0 = *(const float4*)&Opart[g];
    const float4 a1 = *(const float4*)&Opart[g + 4194304];    // split stride
    const float4 li = *(const float4*)&Linv[b * 4096 + q4];
    float4 o;
    o.x = (a0.x + a1.x) * li.x;
    o.y = (a0.y + a1.y) * li.y;
    o.z = (a0.z + a1.z) * li.z;
    o.w = (a0.w + a1.w) * li.w;
    const size_t base = (c < 256)
        ? ((size_t)b * 1048576 + (size_t)c * 4096 + q4)
        : (2097152u + (size_t)b * 1048576 + (size_t)(c - 256) * 4096 + q4);
    *(float4*)&out[base] = o;
}

// ---------------------------------------------------------------------------
// Kernel 3 fallback (ws too small for split-K): round-4 proven 128c x 64q.
// ---------------------------------------------------------------------------
__global__ __launch_bounds__(256) void attn_o_small(
    const bf16* __restrict__ Vall, const bf16* __restrict__ Pt,
    const float* __restrict__ Linv, float* __restrict__ out)
{
    __shared__ __align__(16) bf16 As[128 * 32];
    __shared__ __align__(16) bf16 Bs[64 * 32];

    const int b  = blockIdx.z;
    const int c0 = blockIdx.y * 128;
    const int q0 = blockIdx.x * 64;
    const bf16* A = Vall + (size_t)b * 512 * 4096;
    const bf16* B = Pt   + (size_t)b * 4096 * 4096;

    const int tid = threadIdx.x;
    const int wv = tid >> 6, lane = tid & 63, l16 = lane & 15, quad = lane >> 4;
    const int wr = wv >> 1, wc = wv & 1;

    f32x4 acc[4][2] = {};

    const int arow = tid >> 2, akc = tid & 3;
    for (int ks = 0; ks < 128; ks++) {
        const int k0 = ks * 32;
        gld_lds16(A + (c0 + arow) * 4096 + k0 + akc * 8, As + tid * 8);
        gld_lds16(A + (c0 + 64 + arow) * 4096 + k0 + akc * 8, As + 2048 + tid * 8);
        gld_lds16(B + (q0 + arow) * 4096 + k0 + akc * 8, Bs + tid * 8);
        __syncthreads();
        bf16x8 af[4], bfr[2];
        for (int t = 0; t < 4; t++)
            af[t]  = *(const bf16x8*)&As[(wr * 64 + t * 16 + l16) * 32 + quad * 8];
        for (int t = 0; t < 2; t++)
            bfr[t] = *(const bf16x8*)&Bs[(wc * 32 + t * 16 + l16) * 32 + quad * 8];
        for (int ti = 0; ti < 4; ti++)
            for (int tj = 0; tj < 2; tj++)
                acc[ti][tj] = __builtin_amdgcn_mfma_f32_16x16x32_bf16(af[ti], bfr[tj], acc[ti][tj], 0, 0, 0);
        __syncthreads();
    }

    float rl[2];
    for (int tj = 0; tj < 2; tj++)
        rl[tj] = Linv[b * 4096 + q0 + wc * 32 + tj * 16 + l16];

    for (int ti = 0; ti < 4; ti++) {
        for (int r = 0; r < 4; r++) {
            const int c_ = c0 + wr * 64 + ti * 16 + quad * 4 + r;
            const size_t base = (c_ < 256)
                ? ((size_t)b * 1048576 + (size_t)c_ * 4096)
                : (2097152u + (size_t)b * 1048576 + (size_t)(c_ - 256) * 4096);
            for (int tj = 0; tj < 2; tj++) {
                const int q = q0 + wc * 32 + tj * 16 + l16;
                out[base + q] = acc[ti][tj][r] * rl[tj];
            }
        }
    }
}

// ---------------------------------------------------------------------------
// ws: [0,4)M Q | [4,8)M Kt | [8,16)M Vall | [16,80)M Pt |
//     [80,82)M Lpart [2][4096][64] | [82M,+32K) Linv | [83,147)M Opart (opt)
// ---------------------------------------------------------------------------
extern "C" void kernel_launch(void* const* d_in, const int* in_sizes, int n_in,
                              void* d_out, int out_size, void* d_ws, size_t ws_size,
                              hipStream_t stream)
{
    const float* img = (const float*)d_in[0];
    const float* pc  = (const float*)d_in[1];
    const float* Wq  = (const float*)d_in[2];
    const float* bq  = (const float*)d_in[3];
    const float* Wk  = (const float*)d_in[4];
    const float* bk  = (const float*)d_in[5];
    const float* Wvi = (const float*)d_in[6];
    const float* bvi = (const float*)d_in[7];
    const float* Wvp = (const float*)d_in[8];
    const float* bvp = (const float*)d_in[9];

    char* ws = (char*)d_ws;
    bf16*  Qw    = (bf16*)(ws);
    bf16*  Ktw   = (bf16*)(ws + (4ull  << 20));
    bf16*  Vall  = (bf16*)(ws + (8ull  << 20));
    bf16*  Pt    = (bf16*)(ws + (16ull << 20));
    float* Lpart = (float*)(ws + (80ull << 20));
    float* Linv  = (float*)(ws + (82ull << 20));
    float* Opart = (float*)(ws + (83ull << 20));

    proj_kernel<<<512, 256, 0, stream>>>(img, pc, Wq, bq, Wk, bk,
                                         Wvi, bvi, Wvp, bvp, Qw, Ktw, Vall);
    attn_s_kernel<<<dim3(32, 32, 2), 256, 0, stream>>>(Qw, Ktw, Pt, Lpart);
    lred_kernel<<<32, 256, 0, stream>>>(Lpart, Linv);
    if (ws_size >= (148ull << 20)) {
        attn_o_splitk<<<dim3(64, 4, 4), 256, 0, stream>>>(Pt, Vall, Opart);
        reduce_kernel<<<4096, 256, 0, stream>>>(Opart, Linv, (float*)d_out);
    } else {
        attn_o_small<<<dim3(64, 4, 2), 256, 0, stream>>>(Vall, Pt, Linv, (float*)d_out);
    }
}

// Round 7
// 238.352 us; speedup vs baseline: 1.0750x; 1.0750x over previous
//
#include <hip/hip_runtime.h>
#include <hip/hip_bf16.h>

// B=2, IMG_DIM=VOXEL_DIM=QK_DIM=256, H=W=64, N=4096.
// Inputs/outputs FP32; internal GEMMs bf16 MFMA (16x16x32).

typedef __hip_bfloat16 bf16;
typedef __attribute__((ext_vector_type(8))) short bf16x8;   // 8 bf16 = 4 VGPRs
typedef __attribute__((ext_vector_type(4))) float f32x4;

#define AS1 __attribute__((address_space(1)))
#define AS3 __attribute__((address_space(3)))

__device__ __forceinline__ void gld_lds16(const bf16* g, bf16* s) {
    // async global->LDS, 16B/lane; LDS dst = wave-uniform base + lane*16
    __builtin_amdgcn_global_load_lds((const AS1 void*)g, (AS3 void*)s, 16, 0, 0);
}

__device__ __forceinline__ bf16x8 cvt8(const float* __restrict__ p) {
    const float4 a = *(const float4*)p;
    const float4 b = *(const float4*)(p + 4);
    bf16 t[8];
    t[0] = __float2bfloat16(a.x); t[1] = __float2bfloat16(a.y);
    t[2] = __float2bfloat16(a.z); t[3] = __float2bfloat16(a.w);
    t[4] = __float2bfloat16(b.x); t[5] = __float2bfloat16(b.y);
    t[6] = __float2bfloat16(b.z); t[7] = __float2bfloat16(b.w);
    return *(const bf16x8*)t;
}

// Conflict-free LDS chunk swizzle for BK=32 tiles (measured r5: conflicts -> 0)
__device__ __forceinline__ int chunk_of(int row, int kc) {
    return ((row >> 3) << 5) + (kc << 3) + (row & 7);
}

// ---------------------------------------------------------------------------
// Kernel 1: projections. 512 blocks: blk = s*256 + b*128 + g*64 + ntile.
//   g=0: Q/Kt [n][o] (acc rows = o, packed b64 stores)
//   g=1: V    [o][p] (acc rows = n=p, packed b64 stores)
// img staging: coalesced dword loads + packed b64 XT writes (was 16-way
// bank-conflicted scalar stores).
// ---------------------------------------------------------------------------
__global__ __launch_bounds__(256) void proj_kernel(
    const float* __restrict__ img, const float* __restrict__ pc,
    const float* __restrict__ Wq,  const float* __restrict__ bq,
    const float* __restrict__ Wk,  const float* __restrict__ bk,
    const float* __restrict__ Wvi, const float* __restrict__ bvi,
    const float* __restrict__ Wvp, const float* __restrict__ bvp,
    bf16* __restrict__ Qw, bf16* __restrict__ Ktw, bf16* __restrict__ Vall)
{
    __shared__ __align__(16) bf16 XT[64][264];   // [pos][cin], row = 528B (16B-mult)

    const int blk = blockIdx.x;
    const int s   = blk >> 8;
    const int b   = (blk >> 7) & 1;
    const int g   = (blk >> 6) & 1;
    const int n0  = (blk & 63) * 64;
    const int tid = threadIdx.x;

    if (s == 0) {
        const float* src = img + b * 1048576;                 // [256][4096]
        for (int k = 0; k < 16; k++) {
            const int n  = tid & 63;
            const int c0 = ((tid >> 6) + k * 4) * 4;          // 0..252 step 4
            bf16 pv[4];
            for (int j = 0; j < 4; j++)                       // coalesced over n
                pv[j] = __float2bfloat16(src[(c0 + j) * 4096 + n0 + n]);
            *(uint2*)&XT[n][c0] = *(const uint2*)pv;
        }
    } else {
        // pc[b][d][h][w][c]: ch = c*16+d, flat = d*65536 + n*16 + c
        const float* src = pc + b * 1048576;
        for (int k = 0; k < 16; k++) {
            const int d = k, u = tid;
            const int nl = u >> 2, c4 = (u & 3) * 4;
            const float4 v = *(const float4*)&src[d * 65536 + (n0 + nl) * 16 + c4];
            XT[nl][(c4 + 0) * 16 + d] = __float2bfloat16(v.x);
            XT[nl][(c4 + 1) * 16 + d] = __float2bfloat16(v.y);
            XT[nl][(c4 + 2) * 16 + d] = __float2bfloat16(v.z);
            XT[nl][(c4 + 3) * 16 + d] = __float2bfloat16(v.w);
        }
    }
    __syncthreads();

    const float* W  = s ? (g ? Wvp : Wk) : (g ? Wvi : Wq);
    const float* Bv = s ? (g ? bvp : bk) : (g ? bvi : bq);

    const int wv = tid >> 6, lane = tid & 63, l16 = lane & 15, quad = lane >> 4;
    const int ob = wv * 64;

    f32x4 acc[4][4] = {};

    for (int ks = 0; ks < 8; ks++) {
        const int k0 = ks * 32;
        bf16x8 af[4], wf[4];
        for (int ti = 0; ti < 4; ti++)
            af[ti] = *(const bf16x8*)&XT[ti * 16 + l16][k0 + quad * 8];
        for (int tj = 0; tj < 4; tj++)
            wf[tj] = cvt8(&W[(ob + tj * 16 + l16) * 256 + k0 + quad * 8]);
        if (g == 0) {
            for (int ti = 0; ti < 4; ti++)
                for (int tj = 0; tj < 4; tj++)
                    acc[ti][tj] = __builtin_amdgcn_mfma_f32_16x16x32_bf16(wf[tj], af[ti], acc[ti][tj], 0, 0, 0);
        } else {
            for (int ti = 0; ti < 4; ti++)
                for (int tj = 0; tj < 4; tj++)
                    acc[ti][tj] = __builtin_amdgcn_mfma_f32_16x16x32_bf16(af[ti], wf[tj], acc[ti][tj], 0, 0, 0);
        }
    }

    if (g == 0) {
        bf16* D1 = (s ? Ktw : Qw) + b * (4096 * 256);          // [n][o]
        for (int tj = 0; tj < 4; tj++) {
            const int o0 = ob + tj * 16 + quad * 4;
            const float4 bi = *(const float4*)&Bv[o0];
            for (int ti = 0; ti < 4; ti++) {
                const int n = n0 + ti * 16 + l16;
                bf16 pv[4];
                pv[0] = __float2bfloat16(acc[ti][tj][0] + bi.x);
                pv[1] = __float2bfloat16(acc[ti][tj][1] + bi.y);
                pv[2] = __float2bfloat16(acc[ti][tj][2] + bi.z);
                pv[3] = __float2bfloat16(acc[ti][tj][3] + bi.w);
                *(uint2*)&D1[n * 256 + o0] = *(const uint2*)pv;
            }
        }
    } else {
        bf16* D2 = Vall + b * (512 * 4096) + (s ? 256 * 4096 : 0);  // [c'][p]
        for (int tj = 0; tj < 4; tj++) {
            const int o = ob + tj * 16 + l16;
            const float bias = Bv[o];
            for (int ti = 0; ti < 4; ti++) {
                const int nl = ti * 16 + quad * 4;             // D row = quad*4+r
                bf16 pv[4];
                for (int r = 0; r < 4; r++)
                    pv[r] = __float2bfloat16(acc[ti][tj][r] + bias);
                *(uint2*)&D2[o * 4096 + n0 + nl] = *(const uint2*)pv;
            }
        }
    }
}

// ---------------------------------------------------------------------------
// Kernel 2: S^T = Kt.Q^T (A = Kt rows p, B = Q rows q; K=256) so the 4 acc
// regs are a p-run -> packed 8B stores of Pt[q][p] = exp(S). gld_lds staging
// with conflict-free swizzle. Lpart[b][q][strip64] via quad shuffles.
// No max-subtraction: |S| <= ~10; clamp 80 inert.
// ---------------------------------------------------------------------------
__global__ __launch_bounds__(256) void attn_s_kernel(
    const bf16* __restrict__ Qw, const bf16* __restrict__ Ktw,
    bf16* __restrict__ Pt, float* __restrict__ Lpart)
{
    __shared__ __align__(16) bf16 As[128 * 32];   // Kt rows (p)
    __shared__ __align__(16) bf16 Bs[128 * 32];   // Q rows (q)

    const int b  = blockIdx.z;
    const int p0 = blockIdx.x * 128;
    const int q0 = blockIdx.y * 128;
    const bf16* A = Ktw + b * (4096 * 256);
    const bf16* B = Qw  + b * (4096 * 256);

    const int tid = threadIdx.x;
    const int wv = tid >> 6, lane = tid & 63, l16 = lane & 15, quad = lane >> 4;
    const int wr = wv >> 1, wc = wv & 1;          // wr: p-half, wc: q-half

    const int srow = ((tid >> 5) << 3) | (tid & 7);   // staging row 0..63
    const int skc  = (tid >> 3) & 3;

    f32x4 acc[4][4] = {};

    for (int ks = 0; ks < 8; ks++) {
        const int k0 = ks * 32;
        gld_lds16(A + (p0 + srow     ) * 256 + k0 + skc * 8, As + tid * 8);
        gld_lds16(A + (p0 + 64 + srow) * 256 + k0 + skc * 8, As + (256 + tid) * 8);
        gld_lds16(B + (q0 + srow     ) * 256 + k0 + skc * 8, Bs + tid * 8);
        gld_lds16(B + (q0 + 64 + srow) * 256 + k0 + skc * 8, Bs + (256 + tid) * 8);
        __syncthreads();
        bf16x8 af[4], bfr[4];
        for (int t = 0; t < 4; t++) {
            const int Ra = wr * 64 + t * 16 + l16;
            const int Rb = wc * 64 + t * 16 + l16;
            af[t]  = *(const bf16x8*)&As[chunk_of(Ra, quad) * 8];
            bfr[t] = *(const bf16x8*)&Bs[chunk_of(Rb, quad) * 8];
        }
        for (int ti = 0; ti < 4; ti++)
            for (int tj = 0; tj < 4; tj++)
                acc[ti][tj] = __builtin_amdgcn_mfma_f32_16x16x32_bf16(af[ti], bfr[tj], acc[ti][tj], 0, 0, 0);
        __syncthreads();
    }

    bf16* Pdst = Pt + (size_t)b * 4096 * 4096;
    float lsum[4] = {0.f, 0.f, 0.f, 0.f};        // per tj (fixed q per lane)
    for (int ti = 0; ti < 4; ti++) {
        const int pr = p0 + wr * 64 + ti * 16 + quad * 4;
        for (int tj = 0; tj < 4; tj++) {
            const int q = q0 + wc * 64 + tj * 16 + l16;
            bf16 pv[4];
            float su = 0.0f;
            for (int r = 0; r < 4; r++) {
                const float e = __expf(fminf(acc[ti][tj][r], 80.0f));
                su += e;
                pv[r] = __float2bfloat16(e);
            }
            lsum[tj] += su;
            *(uint2*)&Pdst[(size_t)q * 4096 + pr] = *(const uint2*)pv;
        }
    }
    for (int tj = 0; tj < 4; tj++) {
        float v = lsum[tj];
        v += __shfl_xor(v, 16);
        v += __shfl_xor(v, 32);
        if (quad == 0) {
            const int q = q0 + wc * 64 + tj * 16 + l16;
            Lpart[(size_t)(b * 4096 + q) * 64 + blockIdx.x * 2 + wr] = v;
        }
    }
}

// ---------------------------------------------------------------------------
// Kernel 2b: Linv[b][q] = 1 / sum_strip Lpart  (8192 rows x 64 strips)
// ---------------------------------------------------------------------------
__global__ __launch_bounds__(256) void lred_kernel(
    const float* __restrict__ Lpart, float* __restrict__ Linv)
{
    const int row = blockIdx.x * 256 + threadIdx.x;           // [0, 8192)
    const float4* lp = (const float4*)&Lpart[(size_t)row * 64];
    float s = 0.0f;
    for (int i = 0; i < 16; i++) {
        const float4 v = lp[i];
        s += v.x + v.y + v.z + v.w;
    }
    Linv[row] = 1.0f / fmaxf(s, 1e-30f);
}

// ---------------------------------------------------------------------------
// Kernel 3a: O^T partials. A = Pt (128 q-rows), B = Vall (128 c-rows), BK=32,
// split-K=4 -> grid (32,4,8) = 1024 blocks, 4 blocks/CU (r5 tile, 2x blocks).
// fp32 partials [s][b][c][q] (8 x 8MiB), packed f32x4 stores (q-run regs).
// ---------------------------------------------------------------------------
__global__ __launch_bounds__(256, 4) void attn_o_splitk(
    const bf16* __restrict__ Pt, const bf16* __restrict__ Vall,
    float* __restrict__ Opart)
{
    __shared__ __align__(16) bf16 As[128 * 32];   // Pt rows (q)
    __shared__ __align__(16) bf16 Bs[128 * 32];   // Vall rows (c)

    const int z = blockIdx.z;                     // b*4 + split
    const int b = z >> 2, s = z & 3;
    const int q0 = blockIdx.x * 128;
    const int c0 = blockIdx.y * 128;
    const bf16* A  = Pt   + (size_t)b * 4096 * 4096;
    const bf16* Bp = Vall + (size_t)b * 512 * 4096;

    const int tid = threadIdx.x;
    const int wv = tid >> 6, lane = tid & 63, l16 = lane & 15, quad = lane >> 4;
    const int wr = wv >> 1, wc = wv & 1;          // wr: q-half, wc: c-half

    const int srow = ((tid >> 5) << 3) | (tid & 7);
    const int skc  = (tid >> 3) & 3;
    const int kbase = s * 1024;

    f32x4 acc[4][4] = {};

    for (int ks = 0; ks < 32; ks++) {
        const int k0 = kbase + ks * 32;
        gld_lds16(A  + (size_t)(q0 + srow     ) * 4096 + k0 + skc * 8, As + tid * 8);
        gld_lds16(A  + (size_t)(q0 + 64 + srow) * 4096 + k0 + skc * 8, As + (256 + tid) * 8);
        gld_lds16(Bp + (size_t)(c0 + srow     ) * 4096 + k0 + skc * 8, Bs + tid * 8);
        gld_lds16(Bp + (size_t)(c0 + 64 + srow) * 4096 + k0 + skc * 8, Bs + (256 + tid) * 8);
        __syncthreads();
        bf16x8 af[4], bfr[4];
        for (int t = 0; t < 4; t++) {
            const int Ra = wr * 64 + t * 16 + l16;
            const int Rb = wc * 64 + t * 16 + l16;
            af[t]  = *(const bf16x8*)&As[chunk_of(Ra, quad) * 8];
            bfr[t] = *(const bf16x8*)&Bs[chunk_of(Rb, quad) * 8];
        }
        for (int ti = 0; ti < 4; ti++)
            for (int tj = 0; tj < 4; tj++)
                acc[ti][tj] = __builtin_amdgcn_mfma_f32_16x16x32_bf16(af[ti], bfr[tj], acc[ti][tj], 0, 0, 0);
        __syncthreads();
    }

    float* Od = Opart + (size_t)(s * 2 + b) * 2097152;        // [c][q] buf
    for (int ti = 0; ti < 4; ti++) {
        const int q = q0 + wr * 64 + ti * 16 + quad * 4;      // q-run of 4
        for (int tj = 0; tj < 4; tj++) {
            const int c = c0 + wc * 64 + tj * 16 + l16;
            *(f32x4*)&Od[(size_t)c * 4096 + q] = acc[ti][tj];
        }
    }
}

// ---------------------------------------------------------------------------
// Kernel 3b: combine 4 splits, apply Linv, scatter to the two outputs.
// ---------------------------------------------------------------------------
__global__ __launch_bounds__(256) void reduce_kernel(
    const float* __restrict__ Opart, const float* __restrict__ Linv,
    float* __restrict__ out)
{
    const int f = blockIdx.x * 256 + threadIdx.x;             // f32x4 index
    const size_t g = (size_t)f * 4;                           // [b][c][q] flat
    const int q4 = (int)(g & 4095);
    const int c  = (int)((g >> 12) & 511);
    const int b  = (int)(g >> 21);
    const float4 a0 = *(const float4*)&Opart[g];
    const float4 a1 = *(const float4*)&Opart[g + 1 * 4194304];
    const float4 a2 = *(const float4*)&Opart[g + 2 * 4194304];
    const float4 a3 = *(const float4*)&Opart[g + 3 * 4194304];
    const float4 li = *(const float4*)&Linv[b * 4096 + q4];
    float4 o;
    o.x = ((a0.x + a1.x) + (a2.x + a3.x)) * li.x;
    o.y = ((a0.y + a1.y) + (a2.y + a3.y)) * li.y;
    o.z = ((a0.z + a1.z) + (a2.z + a3.z)) * li.z;
    o.w = ((a0.w + a1.w) + (a2.w + a3.w)) * li.w;
    const size_t base = (c < 256)
        ? ((size_t)b * 1048576 + (size_t)c * 4096 + q4)
        : (2097152u + (size_t)b * 1048576 + (size_t)(c - 256) * 4096 + q4);
    *(float4*)&out[base] = o;
}

// ---------------------------------------------------------------------------
// Kernel 3 fallback (ws too small for split-K): round-4 proven 128c x 64q.
// ---------------------------------------------------------------------------
__global__ __launch_bounds__(256) void attn_o_small(
    const bf16* __restrict__ Vall, const bf16* __restrict__ Pt,
    const float* __restrict__ Linv, float* __restrict__ out)
{
    __shared__ __align__(16) bf16 As[128 * 32];
    __shared__ __align__(16) bf16 Bs[64 * 32];

    const int b  = blockIdx.z;
    const int c0 = blockIdx.y * 128;
    const int q0 = blockIdx.x * 64;
    const bf16* A = Vall + (size_t)b * 512 * 4096;
    const bf16* B = Pt   + (size_t)b * 4096 * 4096;

    const int tid = threadIdx.x;
    const int wv = tid >> 6, lane = tid & 63, l16 = lane & 15, quad = lane >> 4;
    const int wr = wv >> 1, wc = wv & 1;

    f32x4 acc[4][2] = {};

    const int arow = tid >> 2, akc = tid & 3;
    for (int ks = 0; ks < 128; ks++) {
        const int k0 = ks * 32;
        gld_lds16(A + (c0 + arow) * 4096 + k0 + akc * 8, As + tid * 8);
        gld_lds16(A + (c0 + 64 + arow) * 4096 + k0 + akc * 8, As + 2048 + tid * 8);
        gld_lds16(B + (q0 + arow) * 4096 + k0 + akc * 8, Bs + tid * 8);
        __syncthreads();
        bf16x8 af[4], bfr[2];
        for (int t = 0; t < 4; t++)
            af[t]  = *(const bf16x8*)&As[(wr * 64 + t * 16 + l16) * 32 + quad * 8];
        for (int t = 0; t < 2; t++)
            bfr[t] = *(const bf16x8*)&Bs[(wc * 32 + t * 16 + l16) * 32 + quad * 8];
        for (int ti = 0; ti < 4; ti++)
            for (int tj = 0; tj < 2; tj++)
                acc[ti][tj] = __builtin_amdgcn_mfma_f32_16x16x32_bf16(af[ti], bfr[tj], acc[ti][tj], 0, 0, 0);
        __syncthreads();
    }

    float rl[2];
    for (int tj = 0; tj < 2; tj++)
        rl[tj] = Linv[b * 4096 + q0 + wc * 32 + tj * 16 + l16];

    for (int ti = 0; ti < 4; ti++) {
        for (int r = 0; r < 4; r++) {
            const int c_ = c0 + wr * 64 + ti * 16 + quad * 4 + r;
            const size_t base = (c_ < 256)
                ? ((size_t)b * 1048576 + (size_t)c_ * 4096)
                : (2097152u + (size_t)b * 1048576 + (size_t)(c_ - 256) * 4096);
            for (int tj = 0; tj < 2; tj++) {
                const int q = q0 + wc * 32 + tj * 16 + l16;
                out[base + q] = acc[ti][tj][r] * rl[tj];
            }
        }
    }
}

// ---------------------------------------------------------------------------
// ws: [0,4)M Q | [4,8)M Kt | [8,16)M Vall | [16,80)M Pt |
//     [80,82)M Lpart [2][4096][64] | [82M,+32K) Linv |
//     [83,147)M Opart fp32 [4 splits][2 b][512][4096] (8 x 8 MiB)
// ---------------------------------------------------------------------------
extern "C" void kernel_launch(void* const* d_in, const int* in_sizes, int n_in,
                              void* d_out, int out_size, void* d_ws, size_t ws_size,
                              hipStream_t stream)
{
    const float* img = (const float*)d_in[0];
    const float* pc  = (const float*)d_in[1];
    const float* Wq  = (const float*)d_in[2];
    const float* bq  = (const float*)d_in[3];
    const float* Wk  = (const float*)d_in[4];
    const float* bk  = (const float*)d_in[5];
    const float* Wvi = (const float*)d_in[6];
    const float* bvi = (const float*)d_in[7];
    const float* Wvp = (const float*)d_in[8];
    const float* bvp = (const float*)d_in[9];

    char* ws = (char*)d_ws;
    bf16*  Qw    = (bf16*)(ws);
    bf16*  Ktw   = (bf16*)(ws + (4ull  << 20));
    bf16*  Vall  = (bf16*)(ws + (8ull  << 20));
    bf16*  Pt    = (bf16*)(ws + (16ull << 20));
    float* Lpart = (float*)(ws + (80ull << 20));
    float* Linv  = (float*)(ws + (82ull << 20));
    float* Opart = (float*)(ws + (83ull << 20));

    proj_kernel<<<512, 256, 0, stream>>>(img, pc, Wq, bq, Wk, bk,
                                         Wvi, bvi, Wvp, bvp, Qw, Ktw, Vall);
    attn_s_kernel<<<dim3(32, 32, 2), 256, 0, stream>>>(Qw, Ktw, Pt, Lpart);
    lred_kernel<<<32, 256, 0, stream>>>(Lpart, Linv);
    if (ws_size >= (148ull << 20)) {
        attn_o_splitk<<<dim3(32, 4, 8), 256, 0, stream>>>(Pt, Vall, Opart);
        reduce_kernel<<<4096, 256, 0, stream>>>(Opart, Linv, (float*)d_out);
    } else {
        attn_o_small<<<dim3(64, 4, 2), 256, 0, stream>>>(Vall, Pt, Linv, (float*)d_out);
    }
}

// Round 8
// 229.097 us; speedup vs baseline: 1.1184x; 1.0404x over previous
//
#include <hip/hip_runtime.h>
#include <hip/hip_bf16.h>

// B=2, IMG_DIM=VOXEL_DIM=QK_DIM=256, H=W=64, N=4096.
// Inputs/outputs FP32; internal GEMMs bf16 MFMA (16x16x32).

typedef __hip_bfloat16 bf16;
typedef __attribute__((ext_vector_type(8))) short bf16x8;   // 8 bf16 = 4 VGPRs
typedef __attribute__((ext_vector_type(4))) float f32x4;

#define AS1 __attribute__((address_space(1)))
#define AS3 __attribute__((address_space(3)))

__device__ __forceinline__ void gld_lds16(const bf16* g, bf16* s) {
    // async global->LDS, 16B/lane; LDS dst = wave-uniform base + lane*16
    __builtin_amdgcn_global_load_lds((const AS1 void*)g, (AS3 void*)s, 16, 0, 0);
}

__device__ __forceinline__ bf16x8 cvt8(const float* __restrict__ p) {
    const float4 a = *(const float4*)p;
    const float4 b = *(const float4*)(p + 4);
    bf16 t[8];
    t[0] = __float2bfloat16(a.x); t[1] = __float2bfloat16(a.y);
    t[2] = __float2bfloat16(a.z); t[3] = __float2bfloat16(a.w);
    t[4] = __float2bfloat16(b.x); t[5] = __float2bfloat16(b.y);
    t[6] = __float2bfloat16(b.z); t[7] = __float2bfloat16(b.w);
    return *(const bf16x8*)t;
}

// Conflict-free LDS chunk swizzle for BK=32 tiles (measured r5: conflicts -> 0)
__device__ __forceinline__ int chunk_of(int row, int kc) {
    return ((row >> 3) << 5) + (kc << 3) + (row & 7);
}

// ---------------------------------------------------------------------------
// Kernel 1: projections. 512 blocks: blk = s*256 + b*128 + g*64 + ntile.
// ---------------------------------------------------------------------------
__global__ __launch_bounds__(256) void proj_kernel(
    const float* __restrict__ img, const float* __restrict__ pc,
    const float* __restrict__ Wq,  const float* __restrict__ bq,
    const float* __restrict__ Wk,  const float* __restrict__ bk,
    const float* __restrict__ Wvi, const float* __restrict__ bvi,
    const float* __restrict__ Wvp, const float* __restrict__ bvp,
    bf16* __restrict__ Qw, bf16* __restrict__ Ktw, bf16* __restrict__ Vall)
{
    __shared__ __align__(16) bf16 XT[64][264];   // [pos][cin]

    const int blk = blockIdx.x;
    const int s   = blk >> 8;
    const int b   = (blk >> 7) & 1;
    const int g   = (blk >> 6) & 1;
    const int n0  = (blk & 63) * 64;
    const int tid = threadIdx.x;

    if (s == 0) {
        const float* src = img + b * 1048576;                 // [256][4096]
        for (int k = 0; k < 16; k++) {
            const int n  = tid & 63;
            const int c0 = ((tid >> 6) + k * 4) * 4;          // 0..252 step 4
            bf16 pv[4];
            for (int j = 0; j < 4; j++)                       // coalesced over n
                pv[j] = __float2bfloat16(src[(c0 + j) * 4096 + n0 + n]);
            *(uint2*)&XT[n][c0] = *(const uint2*)pv;
        }
    } else {
        // pc[b][d][h][w][c]: ch = c*16+d, flat = d*65536 + n*16 + c
        const float* src = pc + b * 1048576;
        for (int k = 0; k < 16; k++) {
            const int d = k, u = tid;
            const int nl = u >> 2, c4 = (u & 3) * 4;
            const float4 v = *(const float4*)&src[d * 65536 + (n0 + nl) * 16 + c4];
            XT[nl][(c4 + 0) * 16 + d] = __float2bfloat16(v.x);
            XT[nl][(c4 + 1) * 16 + d] = __float2bfloat16(v.y);
            XT[nl][(c4 + 2) * 16 + d] = __float2bfloat16(v.z);
            XT[nl][(c4 + 3) * 16 + d] = __float2bfloat16(v.w);
        }
    }
    __syncthreads();

    const float* W  = s ? (g ? Wvp : Wk) : (g ? Wvi : Wq);
    const float* Bv = s ? (g ? bvp : bk) : (g ? bvi : bq);

    const int wv = tid >> 6, lane = tid & 63, l16 = lane & 15, quad = lane >> 4;
    const int ob = wv * 64;

    f32x4 acc[4][4] = {};

    for (int ks = 0; ks < 8; ks++) {
        const int k0 = ks * 32;
        bf16x8 af[4], wf[4];
        for (int ti = 0; ti < 4; ti++)
            af[ti] = *(const bf16x8*)&XT[ti * 16 + l16][k0 + quad * 8];
        for (int tj = 0; tj < 4; tj++)
            wf[tj] = cvt8(&W[(ob + tj * 16 + l16) * 256 + k0 + quad * 8]);
        if (g == 0) {
            for (int ti = 0; ti < 4; ti++)
                for (int tj = 0; tj < 4; tj++)
                    acc[ti][tj] = __builtin_amdgcn_mfma_f32_16x16x32_bf16(wf[tj], af[ti], acc[ti][tj], 0, 0, 0);
        } else {
            for (int ti = 0; ti < 4; ti++)
                for (int tj = 0; tj < 4; tj++)
                    acc[ti][tj] = __builtin_amdgcn_mfma_f32_16x16x32_bf16(af[ti], wf[tj], acc[ti][tj], 0, 0, 0);
        }
    }

    if (g == 0) {
        bf16* D1 = (s ? Ktw : Qw) + b * (4096 * 256);          // [n][o]
        for (int tj = 0; tj < 4; tj++) {
            const int o0 = ob + tj * 16 + quad * 4;
            const float4 bi = *(const float4*)&Bv[o0];
            for (int ti = 0; ti < 4; ti++) {
                const int n = n0 + ti * 16 + l16;
                bf16 pv[4];
                pv[0] = __float2bfloat16(acc[ti][tj][0] + bi.x);
                pv[1] = __float2bfloat16(acc[ti][tj][1] + bi.y);
                pv[2] = __float2bfloat16(acc[ti][tj][2] + bi.z);
                pv[3] = __float2bfloat16(acc[ti][tj][3] + bi.w);
                *(uint2*)&D1[n * 256 + o0] = *(const uint2*)pv;
            }
        }
    } else {
        bf16* D2 = Vall + b * (512 * 4096) + (s ? 256 * 4096 : 0);  // [c'][p]
        for (int tj = 0; tj < 4; tj++) {
            const int o = ob + tj * 16 + l16;
            const float bias = Bv[o];
            for (int ti = 0; ti < 4; ti++) {
                const int nl = ti * 16 + quad * 4;             // D row = quad*4+r
                bf16 pv[4];
                for (int r = 0; r < 4; r++)
                    pv[r] = __float2bfloat16(acc[ti][tj][r] + bias);
                *(uint2*)&D2[o * 4096 + n0 + nl] = *(const uint2*)pv;
            }
        }
    }
}

// ---------------------------------------------------------------------------
// Kernel 2: S^T = Kt.Q^T -> Pt[q][p] = exp(S) (packed 8B stores) + Lpart.
// ---------------------------------------------------------------------------
__global__ __launch_bounds__(256) void attn_s_kernel(
    const bf16* __restrict__ Qw, const bf16* __restrict__ Ktw,
    bf16* __restrict__ Pt, float* __restrict__ Lpart)
{
    __shared__ __align__(16) bf16 As[128 * 32];   // Kt rows (p)
    __shared__ __align__(16) bf16 Bs[128 * 32];   // Q rows (q)

    const int b  = blockIdx.z;
    const int p0 = blockIdx.x * 128;
    const int q0 = blockIdx.y * 128;
    const bf16* A = Ktw + b * (4096 * 256);
    const bf16* B = Qw  + b * (4096 * 256);

    const int tid = threadIdx.x;
    const int wv = tid >> 6, lane = tid & 63, l16 = lane & 15, quad = lane >> 4;
    const int wr = wv >> 1, wc = wv & 1;          // wr: p-half, wc: q-half

    const int srow = ((tid >> 5) << 3) | (tid & 7);   // staging row 0..63
    const int skc  = (tid >> 3) & 3;

    f32x4 acc[4][4] = {};

    for (int ks = 0; ks < 8; ks++) {
        const int k0 = ks * 32;
        gld_lds16(A + (p0 + srow     ) * 256 + k0 + skc * 8, As + tid * 8);
        gld_lds16(A + (p0 + 64 + srow) * 256 + k0 + skc * 8, As + (256 + tid) * 8);
        gld_lds16(B + (q0 + srow     ) * 256 + k0 + skc * 8, Bs + tid * 8);
        gld_lds16(B + (q0 + 64 + srow) * 256 + k0 + skc * 8, Bs + (256 + tid) * 8);
        __syncthreads();
        bf16x8 af[4], bfr[4];
        for (int t = 0; t < 4; t++) {
            const int Ra = wr * 64 + t * 16 + l16;
            const int Rb = wc * 64 + t * 16 + l16;
            af[t]  = *(const bf16x8*)&As[chunk_of(Ra, quad) * 8];
            bfr[t] = *(const bf16x8*)&Bs[chunk_of(Rb, quad) * 8];
        }
        for (int ti = 0; ti < 4; ti++)
            for (int tj = 0; tj < 4; tj++)
                acc[ti][tj] = __builtin_amdgcn_mfma_f32_16x16x32_bf16(af[ti], bfr[tj], acc[ti][tj], 0, 0, 0);
        __syncthreads();
    }

    bf16* Pdst = Pt + (size_t)b * 4096 * 4096;
    float lsum[4] = {0.f, 0.f, 0.f, 0.f};        // per tj (fixed q per lane)
    for (int ti = 0; ti < 4; ti++) {
        const int pr = p0 + wr * 64 + ti * 16 + quad * 4;
        for (int tj = 0; tj < 4; tj++) {
            const int q = q0 + wc * 64 + tj * 16 + l16;
            bf16 pv[4];
            float su = 0.0f;
            for (int r = 0; r < 4; r++) {
                const float e = __expf(fminf(acc[ti][tj][r], 80.0f));
                su += e;
                pv[r] = __float2bfloat16(e);
            }
            lsum[tj] += su;
            *(uint2*)&Pdst[(size_t)q * 4096 + pr] = *(const uint2*)pv;
        }
    }
    for (int tj = 0; tj < 4; tj++) {
        float v = lsum[tj];
        v += __shfl_xor(v, 16);
        v += __shfl_xor(v, 32);
        if (quad == 0) {
            const int q = q0 + wc * 64 + tj * 16 + l16;
            Lpart[(size_t)(b * 4096 + q) * 64 + blockIdx.x * 2 + wr] = v;
        }
    }
}

// ---------------------------------------------------------------------------
// Kernel 2b: Linv[b][q] = 1 / sum_strip Lpart  (8192 rows x 64 strips)
// ---------------------------------------------------------------------------
__global__ __launch_bounds__(256) void lred_kernel(
    const float* __restrict__ Lpart, float* __restrict__ Linv)
{
    const int row = blockIdx.x * 256 + threadIdx.x;           // [0, 8192)
    const float4* lp = (const float4*)&Lpart[(size_t)row * 64];
    float s = 0.0f;
    for (int i = 0; i < 16; i++) {
        const float4 v = lp[i];
        s += v.x + v.y + v.z + v.w;
    }
    Linv[row] = 1.0f / fmaxf(s, 1e-30f);
}

// ---------------------------------------------------------------------------
// Kernel 3a: O^T partials. 256q x 256c tile, 512 threads (8 waves, 2q x 4c),
// BK=32, split-K=4 -> grid (16,2,8) = 256 blocks = 1/CU exactly.
// Staged bytes halved vs 128x128: Pt x2 + Vall x16 = 256 MB total.
// ---------------------------------------------------------------------------
__global__ __launch_bounds__(512, 2) void attn_o_splitk(
    const bf16* __restrict__ Pt, const bf16* __restrict__ Vall,
    float* __restrict__ Opart)
{
    __shared__ __align__(16) bf16 As[256 * 32];   // Pt rows (q)
    __shared__ __align__(16) bf16 Bs[256 * 32];   // Vall rows (c)

    const int z = blockIdx.z;                     // b*4 + split
    const int b = z >> 2, s = z & 3;
    const int q0 = blockIdx.x * 256;
    const int c0 = blockIdx.y * 256;
    const bf16* A  = Pt   + (size_t)b * 4096 * 4096;
    const bf16* Bp = Vall + (size_t)b * 512 * 4096;

    const int tid = threadIdx.x;
    const int wv = tid >> 6, lane = tid & 63, l16 = lane & 15, quad = lane >> 4;
    const int wq = wv >> 2, wc4 = wv & 3;         // wave = 128q x 64c quadrant

    const int srow = ((tid >> 5) << 3) | (tid & 7);   // 0..127 (chunk == tid)
    const int skc  = (tid >> 3) & 3;
    const int kbase = s * 1024;

    f32x4 acc[8][4] = {};

    for (int ks = 0; ks < 32; ks++) {
        const int k0 = kbase + ks * 32;
        gld_lds16(A  + (size_t)(q0 + srow      ) * 4096 + k0 + skc * 8, As + tid * 8);
        gld_lds16(A  + (size_t)(q0 + 128 + srow) * 4096 + k0 + skc * 8, As + (512 + tid) * 8);
        gld_lds16(Bp + (size_t)(c0 + srow      ) * 4096 + k0 + skc * 8, Bs + tid * 8);
        gld_lds16(Bp + (size_t)(c0 + 128 + srow) * 4096 + k0 + skc * 8, Bs + (512 + tid) * 8);
        __syncthreads();
        bf16x8 af[8], bfr[4];
        for (int t = 0; t < 8; t++)
            af[t]  = *(const bf16x8*)&As[chunk_of(wq * 128 + t * 16 + l16, quad) * 8];
        for (int t = 0; t < 4; t++)
            bfr[t] = *(const bf16x8*)&Bs[chunk_of(wc4 * 64 + t * 16 + l16, quad) * 8];
        for (int ti = 0; ti < 8; ti++)
            for (int tj = 0; tj < 4; tj++)
                acc[ti][tj] = __builtin_amdgcn_mfma_f32_16x16x32_bf16(af[ti], bfr[tj], acc[ti][tj], 0, 0, 0);
        __syncthreads();
    }

    float* Od = Opart + (size_t)(s * 2 + b) * 2097152;        // [c][q] buf
    for (int ti = 0; ti < 8; ti++) {
        const int q = q0 + wq * 128 + ti * 16 + quad * 4;     // q-run of 4
        for (int tj = 0; tj < 4; tj++) {
            const int c = c0 + wc4 * 64 + tj * 16 + l16;
            *(f32x4*)&Od[(size_t)c * 4096 + q] = acc[ti][tj];
        }
    }
}

// ---------------------------------------------------------------------------
// Kernel 3b: combine 4 splits, apply Linv, scatter to the two outputs.
// ---------------------------------------------------------------------------
__global__ __launch_bounds__(256) void reduce_kernel(
    const float* __restrict__ Opart, const float* __restrict__ Linv,
    float* __restrict__ out)
{
    const int f = blockIdx.x * 256 + threadIdx.x;             // f32x4 index
    const size_t g = (size_t)f * 4;                           // [b][c][q] flat
    const int q4 = (int)(g & 4095);
    const int c  = (int)((g >> 12) & 511);
    const int b  = (int)(g >> 21);
    const float4 a0 = *(const float4*)&Opart[g];
    const float4 a1 = *(const float4*)&Opart[g + 1 * 4194304];
    const float4 a2 = *(const float4*)&Opart[g + 2 * 4194304];
    const float4 a3 = *(const float4*)&Opart[g + 3 * 4194304];
    const float4 li = *(const float4*)&Linv[b * 4096 + q4];
    float4 o;
    o.x = ((a0.x + a1.x) + (a2.x + a3.x)) * li.x;
    o.y = ((a0.y + a1.y) + (a2.y + a3.y)) * li.y;
    o.z = ((a0.z + a1.z) + (a2.z + a3.z)) * li.z;
    o.w = ((a0.w + a1.w) + (a2.w + a3.w)) * li.w;
    const size_t base = (c < 256)
        ? ((size_t)b * 1048576 + (size_t)c * 4096 + q4)
        : (2097152u + (size_t)b * 1048576 + (size_t)(c - 256) * 4096 + q4);
    *(float4*)&out[base] = o;
}

// ---------------------------------------------------------------------------
// Kernel 3 fallback (ws too small for split-K): round-4 proven 128c x 64q.
// ---------------------------------------------------------------------------
__global__ __launch_bounds__(256) void attn_o_small(
    const bf16* __restrict__ Vall, const bf16* __restrict__ Pt,
    const float* __restrict__ Linv, float* __restrict__ out)
{
    __shared__ __align__(16) bf16 As[128 * 32];
    __shared__ __align__(16) bf16 Bs[64 * 32];

    const int b  = blockIdx.z;
    const int c0 = blockIdx.y * 128;
    const int q0 = blockIdx.x * 64;
    const bf16* A = Vall + (size_t)b * 512 * 4096;
    const bf16* B = Pt   + (size_t)b * 4096 * 4096;

    const int tid = threadIdx.x;
    const int wv = tid >> 6, lane = tid & 63, l16 = lane & 15, quad = lane >> 4;
    const int wr = wv >> 1, wc = wv & 1;

    f32x4 acc[4][2] = {};

    const int arow = tid >> 2, akc = tid & 3;
    for (int ks = 0; ks < 128; ks++) {
        const int k0 = ks * 32;
        gld_lds16(A + (c0 + arow) * 4096 + k0 + akc * 8, As + tid * 8);
        gld_lds16(A + (c0 + 64 + arow) * 4096 + k0 + akc * 8, As + 2048 + tid * 8);
        gld_lds16(B + (q0 + arow) * 4096 + k0 + akc * 8, Bs + tid * 8);
        __syncthreads();
        bf16x8 af[4], bfr[2];
        for (int t = 0; t < 4; t++)
            af[t]  = *(const bf16x8*)&As[(wr * 64 + t * 16 + l16) * 32 + quad * 8];
        for (int t = 0; t < 2; t++)
            bfr[t] = *(const bf16x8*)&Bs[(wc * 32 + t * 16 + l16) * 32 + quad * 8];
        for (int ti = 0; ti < 4; ti++)
            for (int tj = 0; tj < 2; tj++)
                acc[ti][tj] = __builtin_amdgcn_mfma_f32_16x16x32_bf16(af[ti], bfr[tj], acc[ti][tj], 0, 0, 0);
        __syncthreads();
    }

    float rl[2];
    for (int tj = 0; tj < 2; tj++)
        rl[tj] = Linv[b * 4096 + q0 + wc * 32 + tj * 16 + l16];

    for (int ti = 0; ti < 4; ti++) {
        for (int r = 0; r < 4; r++) {
            const int c_ = c0 + wr * 64 + ti * 16 + quad * 4 + r;
            const size_t base = (c_ < 256)
                ? ((size_t)b * 1048576 + (size_t)c_ * 4096)
                : (2097152u + (size_t)b * 1048576 + (size_t)(c_ - 256) * 4096);
            for (int tj = 0; tj < 2; tj++) {
                const int q = q0 + wc * 32 + tj * 16 + l16;
                out[base + q] = acc[ti][tj][r] * rl[tj];
            }
        }
    }
}

// ---------------------------------------------------------------------------
// ws: [0,4)M Q | [4,8)M Kt | [8,16)M Vall | [16,80)M Pt |
//     [80,82)M Lpart [2][4096][64] | [82M,+32K) Linv |
//     [83,147)M Opart fp32 [4 splits][2 b][512][4096] (8 x 8 MiB)
// ---------------------------------------------------------------------------
extern "C" void kernel_launch(void* const* d_in, const int* in_sizes, int n_in,
                              void* d_out, int out_size, void* d_ws, size_t ws_size,
                              hipStream_t stream)
{
    const float* img = (const float*)d_in[0];
    const float* pc  = (const float*)d_in[1];
    const float* Wq  = (const float*)d_in[2];
    const float* bq  = (const float*)d_in[3];
    const float* Wk  = (const float*)d_in[4];
    const float* bk  = (const float*)d_in[5];
    const float* Wvi = (const float*)d_in[6];
    const float* bvi = (const float*)d_in[7];
    const float* Wvp = (const float*)d_in[8];
    const float* bvp = (const float*)d_in[9];

    char* ws = (char*)d_ws;
    bf16*  Qw    = (bf16*)(ws);
    bf16*  Ktw   = (bf16*)(ws + (4ull  << 20));
    bf16*  Vall  = (bf16*)(ws + (8ull  << 20));
    bf16*  Pt    = (bf16*)(ws + (16ull << 20));
    float* Lpart = (float*)(ws + (80ull << 20));
    float* Linv  = (float*)(ws + (82ull << 20));
    float* Opart = (float*)(ws + (83ull << 20));

    proj_kernel<<<512, 256, 0, stream>>>(img, pc, Wq, bq, Wk, bk,
                                         Wvi, bvi, Wvp, bvp, Qw, Ktw, Vall);
    attn_s_kernel<<<dim3(32, 32, 2), 256, 0, stream>>>(Qw, Ktw, Pt, Lpart);
    lred_kernel<<<32, 256, 0, stream>>>(Lpart, Linv);
    if (ws_size >= (148ull << 20)) {
        attn_o_splitk<<<dim3(16, 2, 8), 512, 0, stream>>>(Pt, Vall, Opart);
        reduce_kernel<<<4096, 256, 0, stream>>>(Opart, Linv, (float*)d_out);
    } else {
        attn_o_small<<<dim3(64, 4, 2), 256, 0, stream>>>(Vall, Pt, Linv, (float*)d_out);
    }
}